// Round 4
// baseline (46682.748 us; speedup 1.0000x reference)
//
#include <hip/hip_runtime.h>
#include <climits>

#define NPTS 65536
#define NB 32
#define NS 2048
#define NSAMP (NB * NS)
#define EPSBN 1e-5f
#define C1 64
#define C2 128
#define C3 256

// workspace float offsets (stats area, 3584 B)
#define SUM0 0
#define SQ0 64
#define SUM1 128
#define SQ1 256
#define SUM2 384
#define SQ2 640
#define A0O 896
#define T0O 960
#define A1O 1024
#define T1O 1152
#define A2O 1280
#define T2O 1536
#define STATS_BYTES 3584
// multi-WG FPS diagnostic: partials [2][NB][8] u64 at 4096, dead output at 8192
#define PART_BYTE_OFF 4096
#define DIAG_OUT_OFF 8192
#define DIAG_NEED (DIAG_OUT_OFF + (size_t)NB * NS * 3 * 4)

#define FPS_T 512

// ---------------------------------------------------------------------------
// DIAGNOSTIC ONLY: 8-WG-per-batch FPS (rounds 2/3 logic, unchanged). Writes
// into workspace (dead) purely so rocprof reports its duration. Its output is
// never read; correctness cannot be affected.
// ---------------------------------------------------------------------------
#define FPS_G 8
#define MPPT (NPTS / (FPS_G * FPS_T))  // 16
#define FPS_SLAB (NPTS / FPS_G)        // 8192

__global__ __launch_bounds__(FPS_T, 1) void fps_multi_kernel(
    const float* __restrict__ xyz, float* __restrict__ out_xyz,
    unsigned long long* __restrict__ partials) {
  const int blk = blockIdx.x;
  const int m = blk & 31;
  const int b = (m & 7) * 4 + (m >> 3);
  const int g = blk >> 5;
  const int tid = threadIdx.x;
  const float* __restrict__ P = xyz + (size_t)b * NPTS * 3;
  const int base = g * FPS_SLAB;

  __shared__ float4 pts_s[FPS_SLAB];  // 128 KB
  __shared__ float wm_s[FPS_T / 64];
  __shared__ int ib_s;

#pragma unroll
  for (int i = 0; i < MPPT; ++i) {
    const int li = i * FPS_T + tid;
    const float* q = P + (size_t)(base + li) * 3;
    pts_s[li] = make_float4(q[0], q[1], q[2], 0.f);
  }
  float dist[MPPT];
#pragma unroll
  for (int i = 0; i < MPPT; ++i) dist[i] = 1e10f;
  __syncthreads();

  float cx = P[0], cy = P[1], cz = P[2];

  for (int k = 0; k < NS; ++k) {
    if (g == 0 && tid == 0) {
      float* o = out_xyz + ((size_t)b * NS + k) * 3;
      o[0] = cx; o[1] = cy; o[2] = cz;
    }
    float lma = -1.f, lmb = -1.f;
#pragma unroll
    for (int i = 0; i < MPPT; ++i) {
      const float4 q = pts_s[i * FPS_T + tid];
      const float dx = q.x - cx;
      const float dy = q.y - cy;
      const float dz = q.z - cz;
      const float d = __fadd_rn(__fadd_rn(__fmul_rn(dx, dx), __fmul_rn(dy, dy)),
                                __fmul_rn(dz, dz));
      const float nd = fminf(dist[i], d);
      dist[i] = nd;
      if (i & 1) lmb = fmaxf(lmb, nd); else lma = fmaxf(lma, nd);
    }
    const float lmy = fmaxf(lma, lmb);
    float wmx = lmy;
#pragma unroll
    for (int off = 32; off > 0; off >>= 1) wmx = fmaxf(wmx, __shfl_xor(wmx, off, 64));
    if ((tid & 63) == 0) wm_s[tid >> 6] = wmx;
    if (tid == 0) ib_s = INT_MAX;
    __syncthreads();
    float bm = wm_s[0];
#pragma unroll
    for (int w = 1; w < FPS_T / 64; ++w) bm = fmaxf(bm, wm_s[w]);
    if (lmy == bm) {
      int myb = INT_MAX;
#pragma unroll
      for (int i = 0; i < MPPT; ++i)
        if (dist[i] == bm) myb = min(myb, base + i * FPS_T + tid);
      atomicMin(&ib_s, myb);
    }
    __syncthreads();
    const int pk = k & 1;
    unsigned long long* slot = partials + ((size_t)pk * NB + b) * FPS_G;
    if (tid == 0) {
      const unsigned long long key =
          ((unsigned long long)__float_as_uint(bm) << 32) |
          ((unsigned long long)(unsigned)(k & 0xFFFF) << 16) |
          (unsigned long long)(unsigned)(65535 - ib_s);
      __hip_atomic_store(&slot[g], key, __ATOMIC_RELEASE, __HIP_MEMORY_SCOPE_AGENT);
    }
    __shared__ unsigned long long part_s[FPS_G];
    if (tid < FPS_G) {
      const unsigned tagk = (unsigned)(k & 0xFFFF);
      unsigned long long v;
      do {
        v = __hip_atomic_load(&slot[tid], __ATOMIC_ACQUIRE, __HIP_MEMORY_SCOPE_AGENT);
      } while (((unsigned)(v >> 16) & 0xFFFFu) != tagk);
      part_s[tid] = v;
    }
    __syncthreads();
    unsigned long long best = part_s[0];
#pragma unroll
    for (int j = 1; j < FPS_G; ++j) best = best > part_s[j] ? best : part_s[j];
    const int widx = 65535 - (int)(best & 0xFFFFull);
    const float* qq = P + (size_t)widx * 3;
    cx = qq[0]; cy = qq[1]; cz = qq[2];
  }
}

// ---------------------------------------------------------------------------
// PRODUCER: single-WG-per-batch FPS — exact round-1 passing logic; only the
// launch bounds changed to (512,1) so dist[128] gets the 256-VGPR budget
// (round 1 at (512,2) spilled: 23 GB fetch + 23 GB write of scratch).
// ---------------------------------------------------------------------------
#define SPPT (NPTS / FPS_T)  // 128

__global__ __launch_bounds__(FPS_T, 1) void fps_single_kernel(
    const float* __restrict__ xyz, float* __restrict__ out_xyz) {
  const int b = blockIdx.x;
  const int tid = threadIdx.x;
  const float* __restrict__ P = xyz + (size_t)b * NPTS * 3;
  __shared__ float cs[3];
  __shared__ float wmax[FPS_T / 64];
  __shared__ int nbest[2];

  float dist[SPPT];
#pragma unroll
  for (int i = 0; i < SPPT; ++i) dist[i] = 1e10f;

  if (tid == 0) {
    cs[0] = P[0]; cs[1] = P[1]; cs[2] = P[2];
    nbest[0] = INT_MAX; nbest[1] = INT_MAX;
  }
  __syncthreads();

  for (int k = 0; k < NS; ++k) {
    const float cx = cs[0], cy = cs[1], cz = cs[2];
    if (tid == 0) {  // emit far_k (pre-update), matching the scan output order
      float* o = out_xyz + ((size_t)b * NS + k) * 3;
      o[0] = cx; o[1] = cy; o[2] = cz;
    }
    float lm0 = -1.f, lm1 = -1.f, lm2 = -1.f, lm3 = -1.f;
#pragma unroll
    for (int i = 0; i < SPPT; ++i) {
      const float* q = P + (size_t)(i * FPS_T + tid) * 3;
      const float dx = q[0] - cx;
      const float dy = q[1] - cy;
      const float dz = q[2] - cz;
      // exact ((dx*dx + dy*dy) + dz*dz), no fma contraction
      const float d = __fadd_rn(__fadd_rn(__fmul_rn(dx, dx), __fmul_rn(dy, dy)),
                                __fmul_rn(dz, dz));
      const float nd = fminf(dist[i], d);
      dist[i] = nd;
      if ((i & 3) == 0) lm0 = fmaxf(lm0, nd);
      else if ((i & 3) == 1) lm1 = fmaxf(lm1, nd);
      else if ((i & 3) == 2) lm2 = fmaxf(lm2, nd);
      else lm3 = fmaxf(lm3, nd);
    }
    float wm = fmaxf(fmaxf(lm0, lm1), fmaxf(lm2, lm3));
#pragma unroll
    for (int off = 32; off > 0; off >>= 1) wm = fmaxf(wm, __shfl_xor(wm, off, 64));
    if ((tid & 63) == 0) wmax[tid >> 6] = wm;
    const int p = k & 1;
    __syncthreads();
    float gmax = wmax[0];
#pragma unroll
    for (int w = 1; w < FPS_T / 64; ++w) gmax = fmaxf(gmax, wmax[w]);
    if (tid == 0) nbest[p ^ 1] = INT_MAX;
    if (wm == gmax) {
      int myb = INT_MAX;
#pragma unroll
      for (int i = 0; i < SPPT; ++i)
        if (dist[i] == gmax) myb = min(myb, i * FPS_T + tid);
      if (myb != INT_MAX) atomicMin(&nbest[p], myb);
    }
    __syncthreads();
    const int nstar = nbest[p];
    if (tid == (nstar & (FPS_T - 1))) {
      const float* q = P + (size_t)nstar * 3;
      cs[0] = q[0]; cs[1] = q[1]; cs[2] = q[2];
    }
    __syncthreads();
  }
}

// ---------------------------------------------------------------------------
// MLP (recompute strategy; workspace only holds per-channel stats)
// ---------------------------------------------------------------------------
__device__ __forceinline__ float wredsum(float v) {
#pragma unroll
  for (int off = 32; off > 0; off >>= 1) v += __shfl_xor(v, off, 64);
  return v;
}
__device__ __forceinline__ float wredmax(float v) {
#pragma unroll
  for (int off = 32; off > 0; off >>= 1) v = fmaxf(v, __shfl_xor(v, off, 64));
  return v;
}

__global__ __launch_bounds__(256) void pass1_kernel(const float* __restrict__ sx,
                                                    const float* __restrict__ w0,
                                                    const float* __restrict__ b0,
                                                    float* __restrict__ acc) {
  const int sg = blockIdx.x * 256 + threadIdx.x;
  const int lane = threadIdx.x & 63;
  const float x0 = sx[(size_t)sg * 3 + 0];
  const float x1 = sx[(size_t)sg * 3 + 1];
  const float x2 = sx[(size_t)sg * 3 + 2];
  float aS = 0.f, aQ = 0.f;
#pragma unroll
  for (int o = 0; o < C1; ++o) {
    const float v = b0[o] + w0[o * 3 + 0] * x0 + w0[o * 3 + 1] * x1 + w0[o * 3 + 2] * x2;
    const float s = wredsum(v);
    const float q = wredsum(v * v);
    if (lane == o) { aS = s; aQ = q; }
  }
  atomicAdd(&acc[SUM0 + lane], aS);
  atomicAdd(&acc[SQ0 + lane], aQ);
}

__global__ void fin_kernel(const float* __restrict__ s, const float* __restrict__ q,
                           const float* __restrict__ g, const float* __restrict__ be,
                           float* __restrict__ a, float* __restrict__ t, int C) {
  const int c = threadIdx.x;
  if (c < C) {
    const float mean = s[c] * (1.0f / NSAMP);
    const float var = q[c] * (1.0f / NSAMP) - mean * mean;
    const float ai = g[c] / sqrtf(var + EPSBN);
    a[c] = ai;
    t[c] = be[c] - mean * ai;
  }
}

__global__ __launch_bounds__(256) void pass2_kernel(const float* __restrict__ sx,
    const float* __restrict__ w0, const float* __restrict__ b0,
    const float* __restrict__ a0, const float* __restrict__ t0,
    const float* __restrict__ w1, const float* __restrict__ b1,
    float* __restrict__ acc) {
  const int sg = blockIdx.x * 256 + threadIdx.x;
  const int lane = threadIdx.x & 63;
  const float x0 = sx[(size_t)sg * 3 + 0];
  const float x1 = sx[(size_t)sg * 3 + 1];
  const float x2 = sx[(size_t)sg * 3 + 2];
  float h[C1];
#pragma unroll
  for (int o = 0; o < C1; ++o) {
    const float v = b0[o] + w0[o * 3 + 0] * x0 + w0[o * 3 + 1] * x1 + w0[o * 3 + 2] * x2;
    h[o] = fmaxf(a0[o] * v + t0[o], 0.f);
  }
  float aS[2] = {0.f, 0.f}, aQ[2] = {0.f, 0.f};
#pragma unroll
  for (int j = 0; j < 2; ++j) {
    for (int oo = 0; oo < 64; ++oo) {
      const int o = j * 64 + oo;
      float v0 = b1[o], v1 = 0.f, v2 = 0.f, v3 = 0.f;
#pragma unroll
      for (int c = 0; c < C1; c += 4) {
        v0 += w1[o * C1 + c + 0] * h[c + 0];
        v1 += w1[o * C1 + c + 1] * h[c + 1];
        v2 += w1[o * C1 + c + 2] * h[c + 2];
        v3 += w1[o * C1 + c + 3] * h[c + 3];
      }
      const float v = (v0 + v1) + (v2 + v3);
      const float sS = wredsum(v);
      const float sQ = wredsum(v * v);
      if (lane == oo) { aS[j] = sS; aQ[j] = sQ; }
    }
  }
#pragma unroll
  for (int j = 0; j < 2; ++j) {
    atomicAdd(&acc[SUM1 + j * 64 + lane], aS[j]);
    atomicAdd(&acc[SQ1 + j * 64 + lane], aQ[j]);
  }
}

__global__ __launch_bounds__(256, 1) void pass3_kernel(const float* __restrict__ sx,
    const float* __restrict__ w0, const float* __restrict__ b0,
    const float* __restrict__ a0, const float* __restrict__ t0,
    const float* __restrict__ w1, const float* __restrict__ b1,
    const float* __restrict__ a1, const float* __restrict__ t1,
    const float* __restrict__ w2, const float* __restrict__ b2,
    float* __restrict__ acc) {
  const int sg = blockIdx.x * 256 + threadIdx.x;
  const int lane = threadIdx.x & 63;
  const float x0 = sx[(size_t)sg * 3 + 0];
  const float x1 = sx[(size_t)sg * 3 + 1];
  const float x2 = sx[(size_t)sg * 3 + 2];
  float h[C1];
#pragma unroll
  for (int o = 0; o < C1; ++o) {
    const float v = b0[o] + w0[o * 3 + 0] * x0 + w0[o * 3 + 1] * x1 + w0[o * 3 + 2] * x2;
    h[o] = fmaxf(a0[o] * v + t0[o], 0.f);
  }
  float f[C2];
#pragma unroll
  for (int o = 0; o < C2; ++o) {
    float v0 = b1[o], v1 = 0.f, v2 = 0.f, v3 = 0.f;
#pragma unroll
    for (int c = 0; c < C1; c += 4) {
      v0 += w1[o * C1 + c + 0] * h[c + 0];
      v1 += w1[o * C1 + c + 1] * h[c + 1];
      v2 += w1[o * C1 + c + 2] * h[c + 2];
      v3 += w1[o * C1 + c + 3] * h[c + 3];
    }
    const float v = (v0 + v1) + (v2 + v3);
    f[o] = fmaxf(a1[o] * v + t1[o], 0.f);
  }
  float aS[4] = {0, 0, 0, 0}, aQ[4] = {0, 0, 0, 0};
#pragma unroll
  for (int j = 0; j < 4; ++j) {
    for (int oo = 0; oo < 64; ++oo) {
      const int o = j * 64 + oo;
      float v0 = b2[o], v1 = 0.f, v2 = 0.f, v3 = 0.f;
#pragma unroll
      for (int c = 0; c < C2; c += 4) {
        v0 += w2[o * C2 + c + 0] * f[c + 0];
        v1 += w2[o * C2 + c + 1] * f[c + 1];
        v2 += w2[o * C2 + c + 2] * f[c + 2];
        v3 += w2[o * C2 + c + 3] * f[c + 3];
      }
      const float v = (v0 + v1) + (v2 + v3);
      const float sS = wredsum(v);
      const float sQ = wredsum(v * v);
      if (lane == oo) { aS[j] = sS; aQ[j] = sQ; }
    }
  }
#pragma unroll
  for (int j = 0; j < 4; ++j) {
    atomicAdd(&acc[SUM2 + j * 64 + lane], aS[j]);
    atomicAdd(&acc[SQ2 + j * 64 + lane], aQ[j]);
  }
}

__global__ __launch_bounds__(256, 1) void pass4_kernel(const float* __restrict__ sx,
    const float* __restrict__ w0, const float* __restrict__ b0,
    const float* __restrict__ a0, const float* __restrict__ t0,
    const float* __restrict__ w1, const float* __restrict__ b1,
    const float* __restrict__ a1, const float* __restrict__ t1,
    const float* __restrict__ w2, const float* __restrict__ b2,
    const float* __restrict__ a2, const float* __restrict__ t2,
    float* __restrict__ feat) {
  const int sg = blockIdx.x * 256 + threadIdx.x;
  const int lane = threadIdx.x & 63;
  const float x0 = sx[(size_t)sg * 3 + 0];
  const float x1 = sx[(size_t)sg * 3 + 1];
  const float x2 = sx[(size_t)sg * 3 + 2];
  float h[C1];
#pragma unroll
  for (int o = 0; o < C1; ++o) {
    const float v = b0[o] + w0[o * 3 + 0] * x0 + w0[o * 3 + 1] * x1 + w0[o * 3 + 2] * x2;
    h[o] = fmaxf(a0[o] * v + t0[o], 0.f);
  }
  float f[C2];
#pragma unroll
  for (int o = 0; o < C2; ++o) {
    float v0 = b1[o], v1 = 0.f, v2 = 0.f, v3 = 0.f;
#pragma unroll
    for (int c = 0; c < C1; c += 4) {
      v0 += w1[o * C1 + c + 0] * h[c + 0];
      v1 += w1[o * C1 + c + 1] * h[c + 1];
      v2 += w1[o * C1 + c + 2] * h[c + 2];
      v3 += w1[o * C1 + c + 3] * h[c + 3];
    }
    const float v = (v0 + v1) + (v2 + v3);
    f[o] = fmaxf(a1[o] * v + t1[o], 0.f);
  }
  float fm[4] = {0, 0, 0, 0};
#pragma unroll
  for (int j = 0; j < 4; ++j) {
    for (int oo = 0; oo < 64; ++oo) {
      const int o = j * 64 + oo;
      float v0 = b2[o], v1 = 0.f, v2 = 0.f, v3 = 0.f;
#pragma unroll
      for (int c = 0; c < C2; c += 4) {
        v0 += w2[o * C2 + c + 0] * f[c + 0];
        v1 += w2[o * C2 + c + 1] * f[c + 1];
        v2 += w2[o * C2 + c + 2] * f[c + 2];
        v3 += w2[o * C2 + c + 3] * f[c + 3];
      }
      const float v = (v0 + v1) + (v2 + v3);
      const float z = fmaxf(a2[o] * v + t2[o], 0.f);  // relu >= 0
      const float m = wredmax(z);
      if (lane == oo) fm[j] = m;
    }
  }
  const int b = sg >> 11;
  unsigned* fb = (unsigned*)feat + (size_t)b * C3;
#pragma unroll
  for (int j = 0; j < 4; ++j)
    atomicMax(&fb[j * 64 + lane], __float_as_uint(fm[j]));
}

// ---------------------------------------------------------------------------
extern "C" void kernel_launch(void* const* d_in, const int* in_sizes, int n_in,
                              void* d_out, int out_size, void* d_ws, size_t ws_size,
                              hipStream_t stream) {
  const float* xyz = (const float*)d_in[0];
  const float* w0 = (const float*)d_in[1];
  const float* b0 = (const float*)d_in[2];
  const float* g0 = (const float*)d_in[3];
  const float* be0 = (const float*)d_in[4];
  const float* w1 = (const float*)d_in[5];
  const float* b1 = (const float*)d_in[6];
  const float* g1 = (const float*)d_in[7];
  const float* be1 = (const float*)d_in[8];
  const float* w2 = (const float*)d_in[9];
  const float* b2 = (const float*)d_in[10];
  const float* g2 = (const float*)d_in[11];
  const float* be2 = (const float*)d_in[12];

  float* out = (float*)d_out;
  float* nx = out;                          // new_xyz [32][2048][3]
  float* feat = out + (size_t)NB * NS * 3;  // features [32][256]
  float* acc = (float*)d_ws;

  hipMemsetAsync(acc, 0, STATS_BYTES, stream);
  hipMemsetAsync(feat, 0, (size_t)NB * C3 * 4, stream);

  // Diagnostic: time the multi-WG FPS into dead workspace (output unread).
  if (ws_size >= DIAG_NEED) {
    unsigned long long* partials =
        (unsigned long long*)((char*)d_ws + PART_BYTE_OFF);
    float* diag_out = (float*)((char*)d_ws + DIAG_OUT_OFF);
    fps_multi_kernel<<<NB * FPS_G, FPS_T, 0, stream>>>(xyz, diag_out, partials);
  }

  // Producer: proven single-WG FPS with spill fix.
  fps_single_kernel<<<NB, FPS_T, 0, stream>>>(xyz, nx);

  const int nblk = NSAMP / 256;
  pass1_kernel<<<nblk, 256, 0, stream>>>(nx, w0, b0, acc);
  fin_kernel<<<1, C1, 0, stream>>>(acc + SUM0, acc + SQ0, g0, be0, acc + A0O, acc + T0O, C1);
  pass2_kernel<<<nblk, 256, 0, stream>>>(nx, w0, b0, acc + A0O, acc + T0O, w1, b1, acc);
  fin_kernel<<<1, C2, 0, stream>>>(acc + SUM1, acc + SQ1, g1, be1, acc + A1O, acc + T1O, C2);
  pass3_kernel<<<nblk, 256, 0, stream>>>(nx, w0, b0, acc + A0O, acc + T0O, w1, b1,
                                         acc + A1O, acc + T1O, w2, b2, acc);
  fin_kernel<<<1, C3, 0, stream>>>(acc + SUM2, acc + SQ2, g2, be2, acc + A2O, acc + T2O, C3);
  pass4_kernel<<<nblk, 256, 0, stream>>>(nx, w0, b0, acc + A0O, acc + T0O, w1, b1,
                                         acc + A1O, acc + T1O, w2, b2,
                                         acc + A2O, acc + T2O, feat);
}

// Round 5
// 38837.485 us; speedup vs baseline: 1.2020x; 1.2020x over previous
//
#include <hip/hip_runtime.h>
#include <climits>

#define NPTS 65536
#define NB 32
#define NS 2048
#define NSAMP (NB * NS)
#define EPSBN 1e-5f
#define C1 64
#define C2 128
#define C3 256

// workspace float offsets (stats area, 3584 B)
#define SUM0 0
#define SQ0 64
#define SUM1 128
#define SQ1 256
#define SUM2 384
#define SQ2 640
#define A0O 896
#define T0O 960
#define A1O 1024
#define T1O 1152
#define A2O 1280
#define T2O 1536
#define STATS_BYTES 3584

// FPS: one 1024-thread WG per batch; dist[64]/thread stays under the
// 128-VGPR cap a 16-wave workgroup implies (16 waves x 128 = full pool).
// Round-4 lesson: 512 threads x dist[128] can never fit (128 regs alone).
#define FPS_T 1024
#define PPT (NPTS / FPS_T)  // 64
#define NWAVE (FPS_T / 64)  // 16

__global__ __launch_bounds__(FPS_T, 1) void fps_kernel(
    const float* __restrict__ xyz, float* __restrict__ out_xyz) {
  const int b = blockIdx.x;
  const int tid = threadIdx.x;
  const float* __restrict__ P = xyz + (size_t)b * NPTS * 3;
  __shared__ float cs[3];
  __shared__ float wmax[NWAVE];
  __shared__ int nbest[2];

  float dist[PPT];
#pragma unroll
  for (int i = 0; i < PPT; ++i) dist[i] = 1e10f;

  if (tid == 0) {
    cs[0] = P[0]; cs[1] = P[1]; cs[2] = P[2];
    nbest[0] = INT_MAX; nbest[1] = INT_MAX;
  }
  __syncthreads();

  for (int k = 0; k < NS; ++k) {
    const float cx = cs[0], cy = cs[1], cz = cs[2];
    if (tid == 0) {  // emit far_k (pre-update), matching the scan output order
      float* o = out_xyz + ((size_t)b * NS + k) * 3;
      o[0] = cx; o[1] = cy; o[2] = cz;
    }
    float lm0 = -1.f, lm1 = -1.f, lm2 = -1.f, lm3 = -1.f;
#pragma unroll
    for (int i = 0; i < PPT; ++i) {
      const float* q = P + (size_t)(i * FPS_T + tid) * 3;
      const float dx = q[0] - cx;
      const float dy = q[1] - cy;
      const float dz = q[2] - cz;
      // exact ((dx*dx + dy*dy) + dz*dz), no fma contraction
      const float d = __fadd_rn(__fadd_rn(__fmul_rn(dx, dx), __fmul_rn(dy, dy)),
                                __fmul_rn(dz, dz));
      const float nd = fminf(dist[i], d);
      dist[i] = nd;
      if ((i & 3) == 0) lm0 = fmaxf(lm0, nd);
      else if ((i & 3) == 1) lm1 = fmaxf(lm1, nd);
      else if ((i & 3) == 2) lm2 = fmaxf(lm2, nd);
      else lm3 = fmaxf(lm3, nd);
    }
    float wm = fmaxf(fmaxf(lm0, lm1), fmaxf(lm2, lm3));
#pragma unroll
    for (int off = 32; off > 0; off >>= 1) wm = fmaxf(wm, __shfl_xor(wm, off, 64));
    if ((tid & 63) == 0) wmax[tid >> 6] = wm;
    const int p = k & 1;
    __syncthreads();  // A: wmax visible
    float gmax = wmax[0];
#pragma unroll
    for (int w = 1; w < NWAVE; ++w) gmax = fmaxf(gmax, wmax[w]);
    if (tid == 0) nbest[p ^ 1] = INT_MAX;  // reset other buffer for next iter
    if (wm == gmax) {  // only wave(s) holding the global max rescan
      int myb = INT_MAX;
#pragma unroll
      for (int i = 0; i < PPT; ++i)
        if (dist[i] == gmax) myb = min(myb, i * FPS_T + tid);
      if (myb != INT_MAX) atomicMin(&nbest[p], myb);
    }
    __syncthreads();  // B: nbest final
    const int nstar = nbest[p];
    if (tid == (nstar & (FPS_T - 1))) {
      const float* q = P + (size_t)nstar * 3;
      cs[0] = q[0]; cs[1] = q[1]; cs[2] = q[2];
    }
    __syncthreads();  // C: cs visible
  }
}

// ---------------------------------------------------------------------------
// MLP (recompute strategy; workspace only holds per-channel stats)
// ---------------------------------------------------------------------------
__device__ __forceinline__ float wredsum(float v) {
#pragma unroll
  for (int off = 32; off > 0; off >>= 1) v += __shfl_xor(v, off, 64);
  return v;
}
__device__ __forceinline__ float wredmax(float v) {
#pragma unroll
  for (int off = 32; off > 0; off >>= 1) v = fmaxf(v, __shfl_xor(v, off, 64));
  return v;
}

__global__ __launch_bounds__(256) void pass1_kernel(const float* __restrict__ sx,
                                                    const float* __restrict__ w0,
                                                    const float* __restrict__ b0,
                                                    float* __restrict__ acc) {
  const int sg = blockIdx.x * 256 + threadIdx.x;
  const int lane = threadIdx.x & 63;
  const float x0 = sx[(size_t)sg * 3 + 0];
  const float x1 = sx[(size_t)sg * 3 + 1];
  const float x2 = sx[(size_t)sg * 3 + 2];
  float aS = 0.f, aQ = 0.f;
#pragma unroll
  for (int o = 0; o < C1; ++o) {
    const float v = b0[o] + w0[o * 3 + 0] * x0 + w0[o * 3 + 1] * x1 + w0[o * 3 + 2] * x2;
    const float s = wredsum(v);
    const float q = wredsum(v * v);
    if (lane == o) { aS = s; aQ = q; }
  }
  atomicAdd(&acc[SUM0 + lane], aS);
  atomicAdd(&acc[SQ0 + lane], aQ);
}

__global__ void fin_kernel(const float* __restrict__ s, const float* __restrict__ q,
                           const float* __restrict__ g, const float* __restrict__ be,
                           float* __restrict__ a, float* __restrict__ t, int C) {
  const int c = threadIdx.x;
  if (c < C) {
    const float mean = s[c] * (1.0f / NSAMP);
    const float var = q[c] * (1.0f / NSAMP) - mean * mean;
    const float ai = g[c] / sqrtf(var + EPSBN);
    a[c] = ai;
    t[c] = be[c] - mean * ai;
  }
}

__global__ __launch_bounds__(256) void pass2_kernel(const float* __restrict__ sx,
    const float* __restrict__ w0, const float* __restrict__ b0,
    const float* __restrict__ a0, const float* __restrict__ t0,
    const float* __restrict__ w1, const float* __restrict__ b1,
    float* __restrict__ acc) {
  const int sg = blockIdx.x * 256 + threadIdx.x;
  const int lane = threadIdx.x & 63;
  const float x0 = sx[(size_t)sg * 3 + 0];
  const float x1 = sx[(size_t)sg * 3 + 1];
  const float x2 = sx[(size_t)sg * 3 + 2];
  float h[C1];
#pragma unroll
  for (int o = 0; o < C1; ++o) {
    const float v = b0[o] + w0[o * 3 + 0] * x0 + w0[o * 3 + 1] * x1 + w0[o * 3 + 2] * x2;
    h[o] = fmaxf(a0[o] * v + t0[o], 0.f);
  }
  float aS[2] = {0.f, 0.f}, aQ[2] = {0.f, 0.f};
#pragma unroll
  for (int j = 0; j < 2; ++j) {
    for (int oo = 0; oo < 64; ++oo) {
      const int o = j * 64 + oo;
      float v0 = b1[o], v1 = 0.f, v2 = 0.f, v3 = 0.f;
#pragma unroll
      for (int c = 0; c < C1; c += 4) {
        v0 += w1[o * C1 + c + 0] * h[c + 0];
        v1 += w1[o * C1 + c + 1] * h[c + 1];
        v2 += w1[o * C1 + c + 2] * h[c + 2];
        v3 += w1[o * C1 + c + 3] * h[c + 3];
      }
      const float v = (v0 + v1) + (v2 + v3);
      const float sS = wredsum(v);
      const float sQ = wredsum(v * v);
      if (lane == oo) { aS[j] = sS; aQ[j] = sQ; }
    }
  }
#pragma unroll
  for (int j = 0; j < 2; ++j) {
    atomicAdd(&acc[SUM1 + j * 64 + lane], aS[j]);
    atomicAdd(&acc[SQ1 + j * 64 + lane], aQ[j]);
  }
}

__global__ __launch_bounds__(256, 1) void pass3_kernel(const float* __restrict__ sx,
    const float* __restrict__ w0, const float* __restrict__ b0,
    const float* __restrict__ a0, const float* __restrict__ t0,
    const float* __restrict__ w1, const float* __restrict__ b1,
    const float* __restrict__ a1, const float* __restrict__ t1,
    const float* __restrict__ w2, const float* __restrict__ b2,
    float* __restrict__ acc) {
  const int sg = blockIdx.x * 256 + threadIdx.x;
  const int lane = threadIdx.x & 63;
  const float x0 = sx[(size_t)sg * 3 + 0];
  const float x1 = sx[(size_t)sg * 3 + 1];
  const float x2 = sx[(size_t)sg * 3 + 2];
  float h[C1];
#pragma unroll
  for (int o = 0; o < C1; ++o) {
    const float v = b0[o] + w0[o * 3 + 0] * x0 + w0[o * 3 + 1] * x1 + w0[o * 3 + 2] * x2;
    h[o] = fmaxf(a0[o] * v + t0[o], 0.f);
  }
  float f[C2];
#pragma unroll
  for (int o = 0; o < C2; ++o) {
    float v0 = b1[o], v1 = 0.f, v2 = 0.f, v3 = 0.f;
#pragma unroll
    for (int c = 0; c < C1; c += 4) {
      v0 += w1[o * C1 + c + 0] * h[c + 0];
      v1 += w1[o * C1 + c + 1] * h[c + 1];
      v2 += w1[o * C1 + c + 2] * h[c + 2];
      v3 += w1[o * C1 + c + 3] * h[c + 3];
    }
    const float v = (v0 + v1) + (v2 + v3);
    f[o] = fmaxf(a1[o] * v + t1[o], 0.f);
  }
  float aS[4] = {0, 0, 0, 0}, aQ[4] = {0, 0, 0, 0};
#pragma unroll
  for (int j = 0; j < 4; ++j) {
    for (int oo = 0; oo < 64; ++oo) {
      const int o = j * 64 + oo;
      float v0 = b2[o], v1 = 0.f, v2 = 0.f, v3 = 0.f;
#pragma unroll
      for (int c = 0; c < C2; c += 4) {
        v0 += w2[o * C2 + c + 0] * f[c + 0];
        v1 += w2[o * C2 + c + 1] * f[c + 1];
        v2 += w2[o * C2 + c + 2] * f[c + 2];
        v3 += w2[o * C2 + c + 3] * f[c + 3];
      }
      const float v = (v0 + v1) + (v2 + v3);
      const float sS = wredsum(v);
      const float sQ = wredsum(v * v);
      if (lane == oo) { aS[j] = sS; aQ[j] = sQ; }
    }
  }
#pragma unroll
  for (int j = 0; j < 4; ++j) {
    atomicAdd(&acc[SUM2 + j * 64 + lane], aS[j]);
    atomicAdd(&acc[SQ2 + j * 64 + lane], aQ[j]);
  }
}

__global__ __launch_bounds__(256, 1) void pass4_kernel(const float* __restrict__ sx,
    const float* __restrict__ w0, const float* __restrict__ b0,
    const float* __restrict__ a0, const float* __restrict__ t0,
    const float* __restrict__ w1, const float* __restrict__ b1,
    const float* __restrict__ a1, const float* __restrict__ t1,
    const float* __restrict__ w2, const float* __restrict__ b2,
    const float* __restrict__ a2, const float* __restrict__ t2,
    float* __restrict__ feat) {
  const int sg = blockIdx.x * 256 + threadIdx.x;
  const int lane = threadIdx.x & 63;
  const float x0 = sx[(size_t)sg * 3 + 0];
  const float x1 = sx[(size_t)sg * 3 + 1];
  const float x2 = sx[(size_t)sg * 3 + 2];
  float h[C1];
#pragma unroll
  for (int o = 0; o < C1; ++o) {
    const float v = b0[o] + w0[o * 3 + 0] * x0 + w0[o * 3 + 1] * x1 + w0[o * 3 + 2] * x2;
    h[o] = fmaxf(a0[o] * v + t0[o], 0.f);
  }
  float f[C2];
#pragma unroll
  for (int o = 0; o < C2; ++o) {
    float v0 = b1[o], v1 = 0.f, v2 = 0.f, v3 = 0.f;
#pragma unroll
    for (int c = 0; c < C1; c += 4) {
      v0 += w1[o * C1 + c + 0] * h[c + 0];
      v1 += w1[o * C1 + c + 1] * h[c + 1];
      v2 += w1[o * C1 + c + 2] * h[c + 2];
      v3 += w1[o * C1 + c + 3] * h[c + 3];
    }
    const float v = (v0 + v1) + (v2 + v3);
    f[o] = fmaxf(a1[o] * v + t1[o], 0.f);
  }
  float fm[4] = {0, 0, 0, 0};
#pragma unroll
  for (int j = 0; j < 4; ++j) {
    for (int oo = 0; oo < 64; ++oo) {
      const int o = j * 64 + oo;
      float v0 = b2[o], v1 = 0.f, v2 = 0.f, v3 = 0.f;
#pragma unroll
      for (int c = 0; c < C2; c += 4) {
        v0 += w2[o * C2 + c + 0] * f[c + 0];
        v1 += w2[o * C2 + c + 1] * f[c + 1];
        v2 += w2[o * C2 + c + 2] * f[c + 2];
        v3 += w2[o * C2 + c + 3] * f[c + 3];
      }
      const float v = (v0 + v1) + (v2 + v3);
      const float z = fmaxf(a2[o] * v + t2[o], 0.f);  // relu >= 0
      const float m = wredmax(z);
      if (lane == oo) fm[j] = m;
    }
  }
  const int b = sg >> 11;
  unsigned* fb = (unsigned*)feat + (size_t)b * C3;
#pragma unroll
  for (int j = 0; j < 4; ++j)
    atomicMax(&fb[j * 64 + lane], __float_as_uint(fm[j]));
}

// ---------------------------------------------------------------------------
extern "C" void kernel_launch(void* const* d_in, const int* in_sizes, int n_in,
                              void* d_out, int out_size, void* d_ws, size_t ws_size,
                              hipStream_t stream) {
  const float* xyz = (const float*)d_in[0];
  const float* w0 = (const float*)d_in[1];
  const float* b0 = (const float*)d_in[2];
  const float* g0 = (const float*)d_in[3];
  const float* be0 = (const float*)d_in[4];
  const float* w1 = (const float*)d_in[5];
  const float* b1 = (const float*)d_in[6];
  const float* g1 = (const float*)d_in[7];
  const float* be1 = (const float*)d_in[8];
  const float* w2 = (const float*)d_in[9];
  const float* b2 = (const float*)d_in[10];
  const float* g2 = (const float*)d_in[11];
  const float* be2 = (const float*)d_in[12];

  float* out = (float*)d_out;
  float* nx = out;                          // new_xyz [32][2048][3]
  float* feat = out + (size_t)NB * NS * 3;  // features [32][256]
  float* acc = (float*)d_ws;

  hipMemsetAsync(acc, 0, STATS_BYTES, stream);
  hipMemsetAsync(feat, 0, (size_t)NB * C3 * 4, stream);

  fps_kernel<<<NB, FPS_T, 0, stream>>>(xyz, nx);

  const int nblk = NSAMP / 256;
  pass1_kernel<<<nblk, 256, 0, stream>>>(nx, w0, b0, acc);
  fin_kernel<<<1, C1, 0, stream>>>(acc + SUM0, acc + SQ0, g0, be0, acc + A0O, acc + T0O, C1);
  pass2_kernel<<<nblk, 256, 0, stream>>>(nx, w0, b0, acc + A0O, acc + T0O, w1, b1, acc);
  fin_kernel<<<1, C2, 0, stream>>>(acc + SUM1, acc + SQ1, g1, be1, acc + A1O, acc + T1O, C2);
  pass3_kernel<<<nblk, 256, 0, stream>>>(nx, w0, b0, acc + A0O, acc + T0O, w1, b1,
                                         acc + A1O, acc + T1O, w2, b2, acc);
  fin_kernel<<<1, C3, 0, stream>>>(acc + SUM2, acc + SQ2, g2, be2, acc + A2O, acc + T2O, C3);
  pass4_kernel<<<nblk, 256, 0, stream>>>(nx, w0, b0, acc + A0O, acc + T0O, w1, b1,
                                         acc + A1O, acc + T1O, w2, b2,
                                         acc + A2O, acc + T2O, feat);
}